// Round 7
// baseline (52.446 us; speedup 1.0000x reference)
//
#include <hip/hip_runtime.h>

// Conv2D 3x3 pad=1: x (32,64,64,64) f32 NCHW, w (128,64,3,3) OIHW, bias(128), out (32,128,64,64) f32.
// Implicit GEMM via bf16 MFMA, big-block LDS-reuse version:
//   prep_x: NCHW f32 -> xT[n][h][w][ci] bf16
//   prep_w: OIHW f32 -> wT[co][p*64+ci] bf16 (p = kh*3+kw)
//   conv_mfma7: grid 256 (1/CU), 512 thr = 8 waves (2 cb x 4 wrow).
//     Block tile 128co x 8h x 64w; wave tile 64co x (2h x 64w), acc 4x8.
//     X [10][66][64ci] staged once (84.5KB); W phased by kh: [3][128co][64ci] 49KB,
//     prefetched at phase start (T14), 2 phase boundaries only. All operands from
//     LDS (0-conflict XOR swizzle) -> kills the 295MB L2 A-frag re-read of r5/r6.

typedef short short8 __attribute__((ext_vector_type(8)));
typedef float f32x4  __attribute__((ext_vector_type(4)));

static __device__ __forceinline__ unsigned short f2bf(float f) {
    unsigned int u = __float_as_uint(f);
    u = (u + 0x7FFFu + ((u >> 16) & 1u)) >> 16;   // RNE
    return (unsigned short)u;
}
static __device__ __forceinline__ unsigned int pk2(float lo, float hi) {
    return (unsigned int)f2bf(lo) | ((unsigned int)f2bf(hi) << 16);
}

// ---------------- prep_x: x[n][ci][h][w] f32 -> xT[n][h][w][ci] bf16 ----------------
__global__ __launch_bounds__(256)
void prep_x(const float* __restrict__ x, unsigned short* __restrict__ xT)
{
    __shared__ float T[64][65];
    const int h = blockIdx.x, n = blockIdx.y, tid = threadIdx.x;
    const size_t nbase = (size_t)n * 262144 + (size_t)h * 64;
    #pragma unroll
    for (int i = 0; i < 16; ++i) {
        int idx = tid + i * 256;           // ci*64 + w
        int ci = idx >> 6, w = idx & 63;
        T[ci][w] = x[nbase + (size_t)ci * 4096 + w];
    }
    __syncthreads();
    const int w = tid >> 2, cg = tid & 3;  // cg: ci group of 16
    unsigned int pk[8];
    #pragma unroll
    for (int k = 0; k < 8; ++k)
        pk[k] = pk2(T[cg * 16 + 2 * k][w], T[cg * 16 + 2 * k + 1][w]);
    unsigned short* dst = xT + (((size_t)n * 64 + h) * 64 + w) * 64 + cg * 16;
    uint4 a; a.x = pk[0]; a.y = pk[1]; a.z = pk[2]; a.w = pk[3];
    uint4 b; b.x = pk[4]; b.y = pk[5]; b.z = pk[6]; b.w = pk[7];
    *(uint4*)(dst)     = a;
    *(uint4*)(dst + 8) = b;
}

// ---------------- prep_w: w[co][ci][kh][kw] f32 -> wT[co][p*64+ci] bf16 ----------------
__global__ __launch_bounds__(256)
void prep_w(const float* __restrict__ w, unsigned short* __restrict__ wT)
{
    int t = blockIdx.x * 256 + threadIdx.x;
    if (t >= 128 * 576) return;
    int co = t / 576, r = t - co * 576;
    int p = r >> 6, ci = r & 63;
    wT[t] = f2bf(w[(size_t)(co * 64 + ci) * 9 + p]);
}

// ---------------- main MFMA conv ----------------
#define XBYTES 84480                    // 10 rows * 66 wp * 64 ci * 2B
#define WBYTES 49152                    // 3 planes * 128 co * 64 ci * 2B
#define TOTAL_LDS (XBYTES + WBYTES)     // 133632

__global__ __launch_bounds__(512, 2)
void conv_mfma7(const unsigned short* __restrict__ xT,
                const unsigned short* __restrict__ wT,
                const float* __restrict__ bias,
                float* __restrict__ out)
{
    extern __shared__ __align__(16) char lds[];
    char* wl = lds + XBYTES;

    const int tid  = threadIdx.x;
    const int h0   = blockIdx.x * 8;
    const int n    = blockIdx.y;
    const int wid  = tid >> 6;          // 0..7
    const int cb   = wid >> 2;          // co half (0..1)
    const int wrow = wid & 3;           // h-pair within tile
    const int lane = tid & 63;
    const int l15  = lane & 15, l4 = lane >> 4;

    const unsigned short* xTn = xT + (size_t)n * 262144;

    // ---- W phase-0 stage: 3072 granules of 16B -> 6 per thread ----
    // granule G: g=G&7 (ci granule), co=(G>>3)&127, pl=G>>10
    {
        uint4 wreg[6];
        #pragma unroll
        for (int k = 0; k < 6; ++k) {
            int G = tid + k * 512;
            int g = G & 7, co = (G >> 3) & 127, pl = G >> 10;
            wreg[k] = *(const uint4*)(wT + co * 576 + (pl * 64 + g * 8));
        }
        #pragma unroll
        for (int k = 0; k < 6; ++k) {
            int G = tid + k * 512;
            int g = G & 7, co = (G >> 3) & 127, pl = G >> 10;
            *(uint4*)(wl + (pl * 128 + co) * 128 + ((g ^ (co & 7)) * 16)) = wreg[k];
        }
    }

    // ---- X stage: 5280 granules of 16B (10 rows x 66 wp x 8 g), XOR-swizzled ----
    {
        uint4 xreg[11];
        #pragma unroll
        for (int k = 0; k < 11; ++k) {
            int G = tid + k * 512;
            if (k < 10 || tid < 160) {
                int hp = G / 528, rem = G - hp * 528;
                int wp = rem >> 3, g = rem & 7;
                int gh = h0 + hp - 1, gw = wp - 1;
                uint4 v; v.x = v.y = v.z = v.w = 0u;
                if ((unsigned)gh < 64u && (unsigned)gw < 64u)
                    v = *(const uint4*)(xTn + ((gh * 64 + gw) * 64 + g * 8));
                xreg[k] = v;
            }
        }
        #pragma unroll
        for (int k = 0; k < 11; ++k) {
            int G = tid + k * 512;
            if (k < 10 || tid < 160) {
                int hp = G / 528, rem = G - hp * 528;
                int wp = rem >> 3, g = rem & 7;
                *(uint4*)(lds + (hp * 66 + wp) * 128 + ((g ^ (wp & 7)) * 16)) = xreg[k];
            }
        }
    }
    __syncthreads();

    f32x4 acc[4][8];
    #pragma unroll
    for (int mf = 0; mf < 4; ++mf)
        #pragma unroll
        for (int nf = 0; nf < 8; ++nf)
            acc[mf][nf] = (f32x4)0.0f;

    #pragma unroll
    for (int ph = 0; ph < 3; ++ph) {        // ph = kh
        // prefetch next phase's W into regs (lands during this phase's MFMAs)
        uint4 wreg[6];
        if (ph < 2) {
            #pragma unroll
            for (int k = 0; k < 6; ++k) {
                int G = tid + k * 512;
                int g = G & 7, co = (G >> 3) & 127, pl = G >> 10;
                wreg[k] = *(const uint4*)(wT + co * 576 + (((ph + 1) * 3 + pl) * 64 + g * 8));
            }
        }

        #pragma unroll
        for (int pl = 0; pl < 3; ++pl) {    // pl = kw
            #pragma unroll
            for (int c = 0; c < 2; ++c) {
                short8 Af[4], Bf[8];
                #pragma unroll
                for (int mf = 0; mf < 4; ++mf) {
                    const int co = cb * 64 + mf * 16 + l15;
                    Af[mf] = *(const short8*)(wl + (pl * 128 + co) * 128 +
                                              (((c * 4 + l4) ^ (co & 7)) * 16));
                }
                #pragma unroll
                for (int nf = 0; nf < 8; ++nf) {
                    const int hp = wrow * 2 + (nf >> 2) + ph;
                    const int wp = (nf & 3) * 16 + l15 + pl;
                    Bf[nf] = *(const short8*)(lds + (hp * 66 + wp) * 128 +
                                              (((c * 4 + l4) ^ (wp & 7)) * 16));
                }
                __builtin_amdgcn_s_setprio(1);
                #pragma unroll
                for (int mf = 0; mf < 4; ++mf)
                    #pragma unroll
                    for (int nf = 0; nf < 8; ++nf)
                        acc[mf][nf] = __builtin_amdgcn_mfma_f32_16x16x32_bf16(
                            Af[mf], Bf[nf], acc[mf][nf], 0, 0, 0);
                __builtin_amdgcn_s_setprio(0);
            }
        }

        if (ph < 2) {
            __syncthreads();   // all waves done READING this phase's W
            #pragma unroll
            for (int k = 0; k < 6; ++k) {
                int G = tid + k * 512;
                int g = G & 7, co = (G >> 3) & 127, pl = G >> 10;
                *(uint4*)(wl + (pl * 128 + co) * 128 + ((g ^ (co & 7)) * 16)) = wreg[k];
            }
            __syncthreads();   // writes visible
        }
    }

    // ---- epilogue: bias + store (C/D: col=lane&15, row=(lane>>4)*4+reg) ----
    #pragma unroll
    for (int mf = 0; mf < 4; ++mf) {
        const f32x4 bv4 = *(const f32x4*)(bias + cb * 64 + mf * 16 + l4 * 4);
        #pragma unroll
        for (int r = 0; r < 4; ++r) {
            const int co = cb * 64 + mf * 16 + l4 * 4 + r;
            const float bv = bv4[r];
            #pragma unroll
            for (int nf = 0; nf < 8; ++nf) {
                const int h = h0 + wrow * 2 + (nf >> 2);
                const int w = (nf & 3) * 16 + l15;
                out[(((size_t)n * 128 + co) * 64 + h) * 64 + w] = acc[mf][nf][r] + bv;
            }
        }
    }
}

// ---------------- fp32 fallback if ws too small ----------------
__global__ __launch_bounds__(256, 4)
void conv2d_f32_tiled(const float* __restrict__ x,
                      const float* __restrict__ wgt,
                      const float* __restrict__ bias,
                      float* __restrict__ out)
{
    __shared__ float Xlds[8][10][66];
    __shared__ float Wlds[32][72];
    const int tid = threadIdx.x;
    const int co0 = blockIdx.x * 32, h0 = blockIdx.y * 8, n = blockIdx.z;
    const int tco = tid >> 6, lane = tid & 63;
    float acc[8][8];
    #pragma unroll
    for (int i = 0; i < 8; ++i)
        #pragma unroll
        for (int j = 0; j < 8; ++j) acc[i][j] = 0.0f;
    for (int cc = 0; cc < 8; ++cc) {
        const int ci0 = cc * 8;
        for (int idx = tid; idx < 8 * 10 * 66; idx += 256) {
            const int ww = idx % 66, t = idx / 66, hh = t % 10, ci = t / 10;
            const int gh = h0 + hh - 1, gw = ww - 1;
            float v = 0.0f;
            if ((unsigned)gh < 64u && (unsigned)gw < 64u)
                v = x[(((size_t)n * 64 + ci0 + ci) * 64 + gh) * 64 + gw];
            Xlds[ci][hh][ww] = v;
        }
        for (int idx = tid; idx < 32 * 72; idx += 256) {
            const int r = idx % 72, co = idx / 72;
            Wlds[co][r] = wgt[(size_t)(co0 + co) * 576 + ci0 * 9 + r];
        }
        __syncthreads();
        for (int ci = 0; ci < 8; ++ci)
            #pragma unroll
            for (int kh = 0; kh < 3; ++kh)
                #pragma unroll
                for (int kw = 0; kw < 3; ++kw) {
                    float wv[8];
                    #pragma unroll
                    for (int i = 0; i < 8; ++i) wv[i] = Wlds[tco * 8 + i][ci * 9 + kh * 3 + kw];
                    #pragma unroll
                    for (int j = 0; j < 8; ++j) {
                        const float xv = Xlds[ci][j + kh][lane + kw];
                        #pragma unroll
                        for (int i = 0; i < 8; ++i) acc[i][j] = fmaf(wv[i], xv, acc[i][j]);
                    }
                }
        __syncthreads();
    }
    #pragma unroll
    for (int i = 0; i < 8; ++i) {
        const int co = co0 + tco * 8 + i;
        const float b = bias[co];
        #pragma unroll
        for (int j = 0; j < 8; ++j)
            out[(((size_t)n * 128 + co) * 64 + (h0 + j)) * 64 + lane] = acc[i][j] + b;
    }
}

extern "C" void kernel_launch(void* const* d_in, const int* in_sizes, int n_in,
                              void* d_out, int out_size, void* d_ws, size_t ws_size,
                              hipStream_t stream)
{
    const float* x    = (const float*)d_in[0];
    const float* wgt  = (const float*)d_in[1];
    const float* bias = (const float*)d_in[2];
    float* out        = (float*)d_out;

    const size_t XT_BYTES = (size_t)32 * 64 * 64 * 64 * 2;   // 33554432
    const size_t WT_BYTES = (size_t)128 * 576 * 2;           // 147456

    if (ws_size < XT_BYTES + WT_BYTES) {
        dim3 grid(4, 8, 32);
        conv2d_f32_tiled<<<grid, 256, 0, stream>>>(x, wgt, bias, out);
        return;
    }

    unsigned short* xT = (unsigned short*)d_ws;
    unsigned short* wT = (unsigned short*)((char*)d_ws + XT_BYTES);

    (void)hipFuncSetAttribute((const void*)conv_mfma7,
                              hipFuncAttributeMaxDynamicSharedMemorySize, TOTAL_LDS);

    prep_x<<<dim3(64, 32), 256, 0, stream>>>(x, xT);
    prep_w<<<dim3((128 * 576 + 255) / 256), 256, 0, stream>>>(wgt, wT);
    conv_mfma7<<<dim3(8, 32), 512, TOTAL_LDS, stream>>>(xT, wT, bias, out);
}

// Round 8
// 44.152 us; speedup vs baseline: 1.1879x; 1.1879x over previous
//
#include <hip/hip_runtime.h>

// Conv2D 3x3 pad=1: x (32,64,64,64) f32 NCHW, w (128,64,3,3) OIHW, bias(128), out (32,128,64,64) f32.
// m97-style implicit GEMM with global_load_lds (width=16) staging:
//   prep_xp: NCHW f32 -> padded+granule-swizzled xP[n][66][66][64ci] bf16 (borders zero)
//   prep_wS: OIHW f32 -> wS[co][p][ci] bf16 with A-side XOR pre-applied
//   conv_mfma8: 256 thr (4 waves = 2cb x 2sh), tile 128co x (2h x 64w), K = 9 planes x 64ci.
//     Per step: stage next plane via 8 global_load_lds x16B (A 16KB + B 16KB, dbuf, 64KB LDS
//     -> 2 blocks/CU), 16 ds_read_b128 + 32 MFMA, one __syncthreads. Zero staging VGPRs.

typedef short short8 __attribute__((ext_vector_type(8)));
typedef float f32x4  __attribute__((ext_vector_type(4)));

static __device__ __forceinline__ unsigned short f2bf(float f) {
    unsigned int u = __float_as_uint(f);
    u = (u + 0x7FFFu + ((u >> 16) & 1u)) >> 16;   // RNE
    return (unsigned short)u;
}
static __device__ __forceinline__ unsigned int pk2(float lo, float hi) {
    return (unsigned int)f2bf(lo) | ((unsigned int)f2bf(hi) << 16);
}
static __device__ __forceinline__ void gload16(const void* g, void* l) {
    __builtin_amdgcn_global_load_lds(
        (const __attribute__((address_space(1))) void*)g,
        (__attribute__((address_space(3))) void*)l, 16, 0, 0);
}

// ---- prep_xp: x[n][ci][h][w] f32 -> xP[n][h'][w'][ci] bf16, padded (66x66), granule-swizzled ----
// granule g (8 ci) of (h',w') stored at slot g ^ (w'&7).  Border rows/cols = 0.
__global__ __launch_bounds__(256)
void prep_xp(const float* __restrict__ x, unsigned short* __restrict__ xP)
{
    const int hp = blockIdx.x, n = blockIdx.y, tid = threadIdx.x;
    unsigned short* rowBase = xP + (((size_t)n * 66 + hp) * 66) * 64;
    if (hp == 0 || hp == 65) {                    // zero border row: 66*64 bf16 = 528 uint4
        uint4 z; z.x = z.y = z.z = z.w = 0u;
        for (int i = tid; i < 528; i += 256) ((uint4*)rowBase)[i] = z;
        return;
    }
    __shared__ float T[64][65];
    const int h = hp - 1;
    const size_t nbase = (size_t)n * 262144 + (size_t)h * 64;
    #pragma unroll
    for (int i = 0; i < 16; ++i) {
        int idx = tid + i * 256;                  // ci*64 + w
        int ci = idx >> 6, w = idx & 63;
        T[ci][w] = x[nbase + (size_t)ci * 4096 + w];
    }
    __syncthreads();
    if (tid < 16) {                               // zero border cols w'=0 and w'=65
        uint4 z; z.x = z.y = z.z = z.w = 0u;
        int wp = (tid >> 3) * 65;
        ((uint4*)(rowBase + wp * 64))[tid & 7] = z;
    }
    const int w = tid >> 2, cg = tid & 3;
    const int wp = w + 1;
    #pragma unroll
    for (int t = 0; t < 2; ++t) {
        const int g = cg * 2 + t;
        uint4 v;
        v.x = pk2(T[g*8+0][w], T[g*8+1][w]);
        v.y = pk2(T[g*8+2][w], T[g*8+3][w]);
        v.z = pk2(T[g*8+4][w], T[g*8+5][w]);
        v.w = pk2(T[g*8+6][w], T[g*8+7][w]);
        *(uint4*)(rowBase + wp * 64 + ((g ^ (wp & 7)) * 8)) = v;
    }
}

// ---- prep_wS: w[co][ci][3][3] f32 -> wS[co][p][slot] bf16, slot gp holds granule gp^(co&7) ----
__global__ __launch_bounds__(256)
void prep_wS(const float* __restrict__ w, unsigned short* __restrict__ wS)
{
    int t = blockIdx.x * 256 + threadIdx.x;       // granule id: (co*9 + p)*8 + gp
    if (t >= 9216) return;
    int gp = t & 7, p = (t >> 3) % 9, co = (t >> 3) / 9;
    int g = gp ^ (co & 7);
    uint4 v;
    const float* src = w + (size_t)(co * 64 + g * 8) * 9 + p;
    v.x = pk2(src[0*9], src[1*9]);
    v.y = pk2(src[2*9], src[3*9]);
    v.z = pk2(src[4*9], src[5*9]);
    v.w = pk2(src[6*9], src[7*9]);
    *(uint4*)(wS + (size_t)t * 8) = v;
}

// ---------------- main MFMA conv ----------------
#define ABYTES 16384                 // 128 co x 128B
#define BBYTES 16384                 // 128 sp x 128B
#define BUFBYTES (ABYTES + BBYTES)   // 32768
#define TOTAL_LDS (2 * BUFBYTES)     // 65536 -> 2 blocks/CU

__global__ __launch_bounds__(256, 3)
void conv_mfma8(const unsigned short* __restrict__ xP,
                const unsigned short* __restrict__ wS,
                const float* __restrict__ bias,
                float* __restrict__ out)
{
    extern __shared__ __align__(16) char lds[];

    const int tid  = threadIdx.x;
    const int bid  = blockIdx.x;                  // 0..1023
    const int swz  = (bid & 7) * 128 + (bid >> 3);// XCD-bijective (1024%8==0)
    const int n    = swz >> 5;
    const int h0   = (swz & 31) * 2;
    const int wid  = tid >> 6, lane = tid & 63;
    const int cb   = wid >> 1;                    // co half
    const int sh   = wid & 1;                     // h row within tile
    const int l15  = lane & 15, l4 = lane >> 4;

    // per-lane staging source bases (wave wid stages co/sp rows [wid*32, wid*32+32))
    const char* aSrc = (const char*)wS +
        ((size_t)(wid * 32 + (lane >> 3)) * 1152 + (lane & 7) * 16);
    const char* bSrc = (const char*)xP +
        ((((size_t)n * 66 + h0 + (wid >> 1)) * 66 + (wid & 1) * 32 + (lane >> 3)) * 128 +
         (lane & 7) * 16);
    // per-wave LDS staging dests
    char* aDst = lds + wid * 4096;
    char* bDst = lds + ABYTES + wid * 4096;

    // ---- prologue: stage plane 0 into buf 0 ----
    #pragma unroll
    for (int k = 0; k < 4; ++k) gload16(aSrc + k * 9216, aDst + k * 1024);
    #pragma unroll
    for (int k = 0; k < 4; ++k) gload16(bSrc + k * 1024, bDst + k * 1024);
    __syncthreads();

    f32x4 acc[4][4];
    #pragma unroll
    for (int mf = 0; mf < 4; ++mf)
        #pragma unroll
        for (int nf = 0; nf < 4; ++nf)
            acc[mf][nf] = (f32x4)0.0f;

    #pragma unroll
    for (int p = 0; p < 9; ++p) {
        const int kw = p % 3;
        // ---- stage next plane into the other buffer (loads fly under compute) ----
        if (p < 8) {
            const int pn  = p + 1;
            const int off = ((pn / 3) * 66 + (pn % 3)) * 128;   // padded (kh,kw) shift
            char* aD = aDst + ((pn & 1) ? BUFBYTES : 0);
            char* bD = bDst + ((pn & 1) ? BUFBYTES : 0);
            #pragma unroll
            for (int k = 0; k < 4; ++k) gload16(aSrc + pn * 128 + k * 9216, aD + k * 1024);
            #pragma unroll
            for (int k = 0; k < 4; ++k) gload16(bSrc + off + k * 1024, bD + k * 1024);
        }

        // ---- compute current buffer ----
        const char* A = lds + ((p & 1) ? BUFBYTES : 0);
        const char* B = A + ABYTES;
        #pragma unroll
        for (int c = 0; c < 2; ++c) {
            short8 Af[4], Bf[4];
            #pragma unroll
            for (int mf = 0; mf < 4; ++mf) {
                const int co = cb * 64 + mf * 16 + l15;
                Af[mf] = *(const short8*)(A + co * 128 + (((c * 4 + l4) ^ (co & 7)) * 16));
            }
            #pragma unroll
            for (int nf = 0; nf < 4; ++nf) {
                const int sp = sh * 64 + nf * 16 + l15;
                Bf[nf] = *(const short8*)(B + sp * 128 + (((c * 4 + l4) ^ ((sp + kw) & 7)) * 16));
            }
            __builtin_amdgcn_s_setprio(1);
            #pragma unroll
            for (int mf = 0; mf < 4; ++mf)
                #pragma unroll
                for (int nf = 0; nf < 4; ++nf)
                    acc[mf][nf] = __builtin_amdgcn_mfma_f32_16x16x32_bf16(
                        Af[mf], Bf[nf], acc[mf][nf], 0, 0, 0);
            __builtin_amdgcn_s_setprio(0);
        }
        __syncthreads();   // next buf staged & this buf free for overwrite
    }

    // ---- epilogue: bias + store (C/D: col=lane&15, row=(lane>>4)*4+reg) ----
    {
        const int h = h0 + sh;
        #pragma unroll
        for (int mf = 0; mf < 4; ++mf) {
            const f32x4 bv4 = *(const f32x4*)(bias + cb * 64 + mf * 16 + l4 * 4);
            #pragma unroll
            for (int r = 0; r < 4; ++r) {
                const int co = cb * 64 + mf * 16 + l4 * 4 + r;
                float* orow = out + (((size_t)n * 128 + co) * 64 + h) * 64;
                #pragma unroll
                for (int nf = 0; nf < 4; ++nf)
                    orow[nf * 16 + l15] = acc[mf][nf][r] + bv4[r];
            }
        }
    }
}

// ---------------- fp32 fallback if ws too small ----------------
__global__ __launch_bounds__(256, 4)
void conv2d_f32_tiled(const float* __restrict__ x,
                      const float* __restrict__ wgt,
                      const float* __restrict__ bias,
                      float* __restrict__ out)
{
    __shared__ float Xlds[8][10][66];
    __shared__ float Wlds[32][72];
    const int tid = threadIdx.x;
    const int co0 = blockIdx.x * 32, h0 = blockIdx.y * 8, n = blockIdx.z;
    const int tco = tid >> 6, lane = tid & 63;
    float acc[8][8];
    #pragma unroll
    for (int i = 0; i < 8; ++i)
        #pragma unroll
        for (int j = 0; j < 8; ++j) acc[i][j] = 0.0f;
    for (int cc = 0; cc < 8; ++cc) {
        const int ci0 = cc * 8;
        for (int idx = tid; idx < 8 * 10 * 66; idx += 256) {
            const int ww = idx % 66, t = idx / 66, hh = t % 10, ci = t / 10;
            const int gh = h0 + hh - 1, gw = ww - 1;
            float v = 0.0f;
            if ((unsigned)gh < 64u && (unsigned)gw < 64u)
                v = x[(((size_t)n * 64 + ci0 + ci) * 64 + gh) * 64 + gw];
            Xlds[ci][hh][ww] = v;
        }
        for (int idx = tid; idx < 32 * 72; idx += 256) {
            const int r = idx % 72, co = idx / 72;
            Wlds[co][r] = wgt[(size_t)(co0 + co) * 576 + ci0 * 9 + r];
        }
        __syncthreads();
        for (int ci = 0; ci < 8; ++ci)
            #pragma unroll
            for (int kh = 0; kh < 3; ++kh)
                #pragma unroll
                for (int kw = 0; kw < 3; ++kw) {
                    float wv[8];
                    #pragma unroll
                    for (int i = 0; i < 8; ++i) wv[i] = Wlds[tco * 8 + i][ci * 9 + kh * 3 + kw];
                    #pragma unroll
                    for (int j = 0; j < 8; ++j) {
                        const float xv = Xlds[ci][j + kh][lane + kw];
                        #pragma unroll
                        for (int i = 0; i < 8; ++i) acc[i][j] = fmaf(wv[i], xv, acc[i][j]);
                    }
                }
        __syncthreads();
    }
    #pragma unroll
    for (int i = 0; i < 8; ++i) {
        const int co = co0 + tco * 8 + i;
        const float b = bias[co];
        #pragma unroll
        for (int j = 0; j < 8; ++j)
            out[(((size_t)n * 128 + co) * 64 + (h0 + j)) * 64 + lane] = acc[i][j] + b;
    }
}

extern "C" void kernel_launch(void* const* d_in, const int* in_sizes, int n_in,
                              void* d_out, int out_size, void* d_ws, size_t ws_size,
                              hipStream_t stream)
{
    const float* x    = (const float*)d_in[0];
    const float* wgt  = (const float*)d_in[1];
    const float* bias = (const float*)d_in[2];
    float* out        = (float*)d_out;

    const size_t XP_BYTES = (size_t)32 * 66 * 66 * 64 * 2;   // 17,842,176
    const size_t WS_BYTES = (size_t)128 * 9 * 64 * 2;        //    147,456

    if (ws_size < XP_BYTES + WS_BYTES) {
        dim3 grid(4, 8, 32);
        conv2d_f32_tiled<<<grid, 256, 0, stream>>>(x, wgt, bias, out);
        return;
    }

    unsigned short* xP = (unsigned short*)d_ws;
    unsigned short* wS = (unsigned short*)((char*)d_ws + XP_BYTES);

    (void)hipFuncSetAttribute((const void*)conv_mfma8,
                              hipFuncAttributeMaxDynamicSharedMemorySize, TOTAL_LDS);

    prep_xp<<<dim3(66, 32), 256, 0, stream>>>(x, xP);
    prep_wS<<<dim3(36), 256, 0, stream>>>(wgt, wS);
    conv_mfma8<<<dim3(1024), 256, TOTAL_LDS, stream>>>(xP, wS, bias, out);
}